// Round 11
// baseline (2566.628 us; speedup 1.0000x reference)
//
#include <hip/hip_runtime.h>
#include <math.h>

#define T_STEPS 4096
#define NB 16          // batch
#define NH 256         // hidden
#define BH (NB * NH)   // 4096 floats per time step
#define DT_STEP 0.1f

typedef __attribute__((ext_vector_type(8))) short short8;
typedef __attribute__((ext_vector_type(4))) float f32x4;
typedef __attribute__((ext_vector_type(4))) unsigned int u32x4;

// ---------------- expm via Taylor series ----------------
__global__ __launch_bounds__(1024) void k_init_S(const float* __restrict__ A,
                                                 float* __restrict__ S) {
    int idx = blockIdx.x * 1024 + threadIdx.x;
    int i = idx >> 8, j = idx & 255;
    S[idx] = A[idx] + (i == j ? 1.0f : 0.0f);
}

__global__ __launch_bounds__(256) void k_expm_term(const float* __restrict__ Pprev,
                                                   const float* __restrict__ A,
                                                   float* __restrict__ Pnew,
                                                   float* __restrict__ S,
                                                   float invk) {
    __shared__ float prow[256];
    int i = blockIdx.x, j = threadIdx.x;
    prow[j] = Pprev[i * 256 + j];
    __syncthreads();
    float acc = 0.f;
#pragma unroll 8
    for (int m = 0; m < 256; ++m) acc = fmaf(prow[m], A[m * 256 + j], acc);
    float v = acc * invk;
    Pnew[i * 256 + j] = v;
    S[i * 256 + j] += v;
}

// ---------------- row-blocked GEMM (unchanged, works) ----------------
__global__ __launch_bounds__(256) void k_gemm_rows(const float* __restrict__ X,
                                                   const float* __restrict__ Wm,
                                                   const float* __restrict__ bias,
                                                   float* __restrict__ Out) {
    __shared__ float4 xs4[16][64];
    const int tid = threadIdx.x;
    const long r0 = (long)blockIdx.x * 16;
    float* xs = (float*)xs4;
#pragma unroll
    for (int rr = 0; rr < 16; ++rr) xs[rr * 256 + tid] = X[(r0 + rr) * 256 + tid];
    __syncthreads();

    float acc[16];
#pragma unroll
    for (int rr = 0; rr < 16; ++rr) acc[rr] = 0.f;

    const float4* wrow = (const float4*)(Wm + tid * 256);
    for (int d4 = 0; d4 < 64; ++d4) {
        float4 w = wrow[d4];
#pragma unroll
        for (int rr = 0; rr < 16; ++rr) {
            float4 xv = xs4[rr][d4];
            acc[rr] = fmaf(w.x, xv.x, acc[rr]);
            acc[rr] = fmaf(w.y, xv.y, acc[rr]);
            acc[rr] = fmaf(w.z, xv.z, acc[rr]);
            acc[rr] = fmaf(w.w, xv.w, acc[rr]);
        }
    }
    float b = bias[tid];
#pragma unroll
    for (int rr = 0; rr < 16; ++rr) Out[(r0 + rr) * 256 + tid] = acc[rr] + b;
}

// ---------------- MFMA scan v4: AGPR-resident E, asm MFMA ----------------
// Same dataflow as v3 (verified): y = E@h, E bf16 A-operand rows=n, h
// broadcast B across 16 cols. 8 waves (2/SIMD), wave owns n-tiles 2w,2w+1,
// 8 independent depth-2 chains. NEW: ef bound to MFMA via "a" constraints ->
// lives in AGPRs, read directly by v_mfma (no per-step v_accvgpr_read
// traffic, which was ~64 VALU instr/wave/step). Zero-C first links via an
// opaque zero tuple (kills 32 v_mov/step). s_nops guard MFMA hazards that
// the compiler can't see inside inline asm. u prefetch depth 3.
__global__ __launch_bounds__(512)
__attribute__((amdgpu_waves_per_eu(2, 2)))
void k_scan_bc3(const float* __restrict__ u,
                const float* S,        // Wexp (f32); no restrict
                float* hidden,
                float* __restrict__ hfin) {
    const int b   = blockIdx.x;
    const int tid = threadIdx.x;
    const int w   = tid >> 6;           // wave 0..7: n-tiles 2w, 2w+1
    const int l   = tid & 63;
    const int lg  = l >> 4;             // k-group 0..3
    const int lr  = l & 15;             // row within n-tile

    __shared__ unsigned int hlds[256];  // 2 x 512B: h as bf16, linear, dbuf
    char* lds = (char*)hlds;

    union Frag { unsigned int u[4]; u32x4 q; short8 v; };

    // ---- A-fragments: E rows for 2 n-tiles x 8 kt (AGPR-resident) ----
    Frag ef[2][8];
#pragma unroll
    for (int j = 0; j < 2; ++j) {
        const int n = ((2 * w + j) << 4) | lr;
#pragma unroll
        for (int kt = 0; kt < 8; ++kt) {
            const int k0 = kt * 32 + lg * 8;
            const float* sp = S + (size_t)n * 256 + k0;
            float e[8];
#pragma unroll
            for (int q = 0; q < 8; ++q)
                e[q] = sp[q] - ((n == k0 + q) ? 1.0f : 0.0f);
#pragma unroll
            for (int r2 = 0; r2 < 4; ++r2) {
                unsigned int pk;
                asm volatile("v_cvt_pk_bf16_f32 %0, %1, %2"
                             : "=v"(pk) : "v"(e[2 * r2]), "v"(e[2 * r2 + 1]));
                ef[j][kt].u[r2] = pk;
            }
        }
    }

    // opaque zero tuple: C-operand of first chain links (non-rematerializable)
    f32x4 zc = {0.f, 0.f, 0.f, 0.f};
    asm volatile("" : "+v"(zc));

    // ---- per-lane owned h element (lanes l and l|8 duplicate) ----
    const int j_own = (l >> 2) & 1;
    const int n_own = ((2 * w + j_own) << 4) | ((l >> 4) << 2) | (l & 3);
    const bool st = ((l & 8) == 0);       // storer lanes
    const bool wrt = ((l & 9) == 0);      // LDS writer lanes (even pair leader)

    if (tid < 256) hlds[tid] = 0u;        // zero both h buffers

    const float* up = u + (size_t)b * NH + n_own;
    float* hp = hidden + (size_t)b * NH + n_own;
    const float* upn = up + 3 * (size_t)BH;   // walking prefetch ptr (depth 3)

    float hval = 0.f;
    float u_cur = up[0];
    float u_p1 = up[BH];
    float u_p2 = up[2 * BH];
    __syncthreads();

    int roff = 0;                         // byte offset of read buffer (0/512)
    for (int t = 0; t < T_STEPS; ++t) {
        float u_in = *upn;
        upn += (t + 4 < T_STEPS) ? BH : 0;

        // B-fragments: h broadcast (same 16B per 16-lane group)
        Frag hb[8];
#pragma unroll
        for (int kt = 0; kt < 8; ++kt)
            hb[kt].v = *(const short8*)(lds + roff + kt * 64 + lg * 16);

        // 16 MFMAs, ef read directly from AGPRs; 8 depth-2 chains.
        f32x4 a00, a01, a02, a03, a10, a11, a12, a13;
        asm volatile(
            "s_nop 3\n\t"
            "v_mfma_f32_16x16x32_bf16 %[d00], %[e00], %[h0], %[z]\n\t"
            "v_mfma_f32_16x16x32_bf16 %[d01], %[e01], %[h1], %[z]\n\t"
            "v_mfma_f32_16x16x32_bf16 %[d02], %[e02], %[h2], %[z]\n\t"
            "v_mfma_f32_16x16x32_bf16 %[d03], %[e03], %[h3], %[z]\n\t"
            "v_mfma_f32_16x16x32_bf16 %[d10], %[e10], %[h0], %[z]\n\t"
            "v_mfma_f32_16x16x32_bf16 %[d11], %[e11], %[h1], %[z]\n\t"
            "v_mfma_f32_16x16x32_bf16 %[d12], %[e12], %[h2], %[z]\n\t"
            "v_mfma_f32_16x16x32_bf16 %[d13], %[e13], %[h3], %[z]\n\t"
            "v_mfma_f32_16x16x32_bf16 %[d00], %[e04], %[h4], %[d00]\n\t"
            "v_mfma_f32_16x16x32_bf16 %[d01], %[e05], %[h5], %[d01]\n\t"
            "v_mfma_f32_16x16x32_bf16 %[d02], %[e06], %[h6], %[d02]\n\t"
            "v_mfma_f32_16x16x32_bf16 %[d03], %[e07], %[h7], %[d03]\n\t"
            "v_mfma_f32_16x16x32_bf16 %[d10], %[e14], %[h4], %[d10]\n\t"
            "v_mfma_f32_16x16x32_bf16 %[d11], %[e15], %[h5], %[d11]\n\t"
            "v_mfma_f32_16x16x32_bf16 %[d12], %[e16], %[h6], %[d12]\n\t"
            "v_mfma_f32_16x16x32_bf16 %[d13], %[e17], %[h7], %[d13]\n\t"
            "s_nop 7\n\t"
            "s_nop 7"
            : [d00]"=&v"(a00), [d01]"=&v"(a01), [d02]"=&v"(a02), [d03]"=&v"(a03),
              [d10]"=&v"(a10), [d11]"=&v"(a11), [d12]"=&v"(a12), [d13]"=&v"(a13)
            : [z]"v"(zc),
              [e00]"a"(ef[0][0].q), [e01]"a"(ef[0][1].q), [e02]"a"(ef[0][2].q),
              [e03]"a"(ef[0][3].q), [e04]"a"(ef[0][4].q), [e05]"a"(ef[0][5].q),
              [e06]"a"(ef[0][6].q), [e07]"a"(ef[0][7].q),
              [e10]"a"(ef[1][0].q), [e11]"a"(ef[1][1].q), [e12]"a"(ef[1][2].q),
              [e13]"a"(ef[1][3].q), [e14]"a"(ef[1][4].q), [e15]"a"(ef[1][5].q),
              [e16]"a"(ef[1][6].q), [e17]"a"(ef[1][7].q),
              [h0]"v"(hb[0].q), [h1]"v"(hb[1].q), [h2]"v"(hb[2].q),
              [h3]"v"(hb[3].q), [h4]"v"(hb[4].q), [h5]"v"(hb[5].q),
              [h6]"v"(hb[6].q), [h7]"v"(hb[7].q));

        // select j_own per accumulator group, tree-add, component select
        f32x4 c0 = j_own ? a10 : a00;
        f32x4 c1 = j_own ? a11 : a01;
        f32x4 c2 = j_own ? a12 : a02;
        f32x4 c3 = j_own ? a13 : a03;
        f32x4 s = (c0 + c1) + (c2 + c3);
        float y01 = (l & 1) ? s[1] : s[0];
        float y23 = (l & 1) ? s[3] : s[2];
        float y   = (l & 2) ? y23 : y01;

        // h += dt * tanh(u - (h + E h));  tanh(x) = 1 - 2/(e^{2x}+1)
        float xa = (u_cur - hval) - y;
        float E2 = __expf(2.0f * xa);
        float th = fmaf(-2.0f, __builtin_amdgcn_rcpf(E2 + 1.0f), 1.0f);
        hval = fmaf(DT_STEP, th, hval);
        if (st) hp[0] = hval;
        hp += BH;

        // pack (n_own even, n_own+1) -> dword into next buffer
        int nb = __builtin_amdgcn_mov_dpp(__float_as_int(hval), 0xB1, 0xF, 0xF, true);
        if (wrt) {
            unsigned int pk;
            asm volatile("v_cvt_pk_bf16_f32 %0, %1, %2"
                         : "=v"(pk) : "v"(hval), "v"(__int_as_float(nb)));
            *(unsigned int*)(lds + (roff ^ 512) + ((n_own >> 1) << 2)) = pk;
        }
        u_cur = u_p1;
        u_p1 = u_p2;
        u_p2 = u_in;
        roff ^= 512;
        __syncthreads();
    }
    if (st) hfin[(size_t)b * NH + n_own] = hval;
}

extern "C" void kernel_launch(void* const* d_in, const int* in_sizes, int n_in,
                              void* d_out, int out_size, void* d_ws, size_t ws_size,
                              hipStream_t stream) {
    const float* x     = (const float*)d_in[0];  // [T,B,D]
    const float* U_w   = (const float*)d_in[1];  // [H,D]
    const float* U_b   = (const float*)d_in[2];  // [H]
    const float* W_log = (const float*)d_in[3];  // [H,H]
    const float* c_w   = (const float*)d_in[4];  // [O,H]
    const float* c_b   = (const float*)d_in[5];  // [O]

    float* out    = (float*)d_out;
    float* hidden = out;                          // stage hidden in d_out, then in-place GEMM
    float* hfin   = out + (long)T_STEPS * BH;     // second output chunk

    float* ws = (float*)d_ws;
    float* S  = ws;                // 65536 floats: Wexp accumulator
    float* Pa = ws + 65536;
    float* Pb = ws + 2 * 65536;
    float* u  = ws + 3 * 65536;    // 16,777,216 floats

    // Wexp = expm(W_log), Taylor K=9 (||W_log||_2 ~ 0.32 -> remainder ~1e-9)
    k_init_S<<<64, 1024, 0, stream>>>(W_log, S);
    const float* prev = W_log;
    float* cur = Pa;
    for (int k = 2; k <= 9; ++k) {
        k_expm_term<<<256, 256, 0, stream>>>(prev, W_log, cur, S, 1.0f / (float)k);
        prev = cur;
        cur = (cur == Pa) ? Pb : Pa;
    }

    // u = x @ U_w^T + U_b
    k_gemm_rows<<<4096, 256, 0, stream>>>(x, U_w, U_b, u);

    // sequential recurrence (AGPR-E asm MFMA), hidden -> d_out
    k_scan_bc3<<<NB, 512, 0, stream>>>(u, S, hidden, hfin);

    // out = hidden @ c_w^T + c_b, in place
    k_gemm_rows<<<4096, 256, 0, stream>>>(hidden, c_w, c_b, hidden);
}

// Round 12
// 2410.850 us; speedup vs baseline: 1.0646x; 1.0646x over previous
//
#include <hip/hip_runtime.h>
#include <math.h>

#define T_STEPS 4096
#define NB 16          // batch
#define NH 256         // hidden
#define BH (NB * NH)   // 4096 floats per time step
#define DT_STEP 0.1f

typedef __attribute__((ext_vector_type(8))) short short8;
typedef __attribute__((ext_vector_type(4))) float f32x4;

// lgkm-only barrier: cross-wave comm is LDS-only (double-buffered h), so the
// vmcnt(0) drain __syncthreads would insert is unnecessary -> the per-step
// hidden-store (HBM ack ~300-900cy) and u-prefetch stay in flight across steps.
#define LBAR() asm volatile("s_waitcnt lgkmcnt(0)\n\ts_barrier" ::: "memory")

// ---------------- expm via Taylor series ----------------
__global__ __launch_bounds__(1024) void k_init_S(const float* __restrict__ A,
                                                 float* __restrict__ S) {
    int idx = blockIdx.x * 1024 + threadIdx.x;
    int i = idx >> 8, j = idx & 255;
    S[idx] = A[idx] + (i == j ? 1.0f : 0.0f);
}

__global__ __launch_bounds__(256) void k_expm_term(const float* __restrict__ Pprev,
                                                   const float* __restrict__ A,
                                                   float* __restrict__ Pnew,
                                                   float* __restrict__ S,
                                                   float invk) {
    __shared__ float prow[256];
    int i = blockIdx.x, j = threadIdx.x;
    prow[j] = Pprev[i * 256 + j];
    __syncthreads();
    float acc = 0.f;
#pragma unroll 8
    for (int m = 0; m < 256; ++m) acc = fmaf(prow[m], A[m * 256 + j], acc);
    float v = acc * invk;
    Pnew[i * 256 + j] = v;
    S[i * 256 + j] += v;
}

// ---------------- row-blocked GEMM (unchanged, works) ----------------
__global__ __launch_bounds__(256) void k_gemm_rows(const float* __restrict__ X,
                                                   const float* __restrict__ Wm,
                                                   const float* __restrict__ bias,
                                                   float* __restrict__ Out) {
    __shared__ float4 xs4[16][64];
    const int tid = threadIdx.x;
    const long r0 = (long)blockIdx.x * 16;
    float* xs = (float*)xs4;
#pragma unroll
    for (int rr = 0; rr < 16; ++rr) xs[rr * 256 + tid] = X[(r0 + rr) * 256 + tid];
    __syncthreads();

    float acc[16];
#pragma unroll
    for (int rr = 0; rr < 16; ++rr) acc[rr] = 0.f;

    const float4* wrow = (const float4*)(Wm + tid * 256);
    for (int d4 = 0; d4 < 64; ++d4) {
        float4 w = wrow[d4];
#pragma unroll
        for (int rr = 0; rr < 16; ++rr) {
            float4 xv = xs4[rr][d4];
            acc[rr] = fmaf(w.x, xv.x, acc[rr]);
            acc[rr] = fmaf(w.y, xv.y, acc[rr]);
            acc[rr] = fmaf(w.z, xv.z, acc[rr]);
            acc[rr] = fmaf(w.w, xv.w, acc[rr]);
        }
    }
    float b = bias[tid];
#pragma unroll
    for (int rr = 0; rr < 16; ++rr) Out[(r0 + rr) * 256 + tid] = acc[rr] + b;
}

// ---------------- MFMA scan v5 = round-10 v3 + lgkm-only barrier ----------------
// y = E@h (E = Wexp - I bf16 A-operand; h broadcast as B across 16 cols).
// 8 waves (2/SIMD): wave w owns n-tiles 2w, 2w+1; 4 accumulators per tile
// (depth-2 chains). h in LDS as 512B linear bf16, double-buffered; broadcast
// ds_reads; ONE lgkm-only barrier per step (the single change vs round 10).
__global__ __launch_bounds__(512)
__attribute__((amdgpu_waves_per_eu(2, 2)))
void k_scan_bc4(const float* __restrict__ u,
                const float* S,        // Wexp (f32); no restrict
                float* hidden,
                float* __restrict__ hfin) {
    const int b   = blockIdx.x;
    const int tid = threadIdx.x;
    const int w   = tid >> 6;           // wave 0..7: n-tiles 2w, 2w+1
    const int l   = tid & 63;
    const int lg  = l >> 4;             // k-group 0..3
    const int lr  = l & 15;             // row within n-tile

    __shared__ unsigned int hlds[256];  // 2 x 512B: h as bf16, linear, dbuf
    char* lds = (char*)hlds;

    union Frag { unsigned int u[4]; short8 v; };

    // ---- A-fragments: E rows for 2 n-tiles x 8 kt = 64 VGPRs ----
    Frag ef[2][8];
#pragma unroll
    for (int j = 0; j < 2; ++j) {
        const int n = ((2 * w + j) << 4) | lr;
#pragma unroll
        for (int kt = 0; kt < 8; ++kt) {
            const int k0 = kt * 32 + lg * 8;
            const float* sp = S + (size_t)n * 256 + k0;
            float e[8];
#pragma unroll
            for (int q = 0; q < 8; ++q)
                e[q] = sp[q] - ((n == k0 + q) ? 1.0f : 0.0f);
#pragma unroll
            for (int r2 = 0; r2 < 4; ++r2) {
                unsigned int pk;
                asm volatile("v_cvt_pk_bf16_f32 %0, %1, %2"
                             : "=v"(pk) : "v"(e[2 * r2]), "v"(e[2 * r2 + 1]));
                ef[j][kt].u[r2] = pk;
            }
        }
    }

    // ---- per-lane owned h element (lanes l and l|8 duplicate) ----
    const int j_own = (l >> 2) & 1;
    const int n_own = ((2 * w + j_own) << 4) | ((l >> 4) << 2) | (l & 3);
    const bool st = ((l & 8) == 0);       // storer lanes
    const bool wrt = ((l & 9) == 0);      // LDS writer lanes (even pair leader)

    if (tid < 256) hlds[tid] = 0u;        // zero both h buffers

    const float* up = u + (size_t)b * NH + n_own;
    float* hp = hidden + (size_t)b * NH + n_own;
    const float* upn = up + 2 * (size_t)BH;   // walking prefetch pointer

    float hval = 0.f;
    float u_cur = up[0];
    float u_nxt = up[BH];
    __syncthreads();

    int roff = 0;                         // byte offset of read buffer (0/512)
    for (int t = 0; t < T_STEPS; ++t) {
        float u_n2 = *upn;
        upn += (t + 3 < T_STEPS) ? BH : 0;

        // B-fragments: h broadcast (same 16B per 16-lane group)
        Frag hb[8];
#pragma unroll
        for (int kt = 0; kt < 8; ++kt)
            hb[kt].v = *(const short8*)(lds + roff + kt * 64 + lg * 16);

        // 16 independent depth-2 chains per SIMD (2 waves x 2 tiles x 4 accs)
        f32x4 a00 = {0,0,0,0}, a01 = {0,0,0,0}, a02 = {0,0,0,0}, a03 = {0,0,0,0};
        f32x4 a10 = {0,0,0,0}, a11 = {0,0,0,0}, a12 = {0,0,0,0}, a13 = {0,0,0,0};
        a00 = __builtin_amdgcn_mfma_f32_16x16x32_bf16(ef[0][0].v, hb[0].v, a00, 0, 0, 0);
        a01 = __builtin_amdgcn_mfma_f32_16x16x32_bf16(ef[0][1].v, hb[1].v, a01, 0, 0, 0);
        a02 = __builtin_amdgcn_mfma_f32_16x16x32_bf16(ef[0][2].v, hb[2].v, a02, 0, 0, 0);
        a03 = __builtin_amdgcn_mfma_f32_16x16x32_bf16(ef[0][3].v, hb[3].v, a03, 0, 0, 0);
        a10 = __builtin_amdgcn_mfma_f32_16x16x32_bf16(ef[1][0].v, hb[0].v, a10, 0, 0, 0);
        a11 = __builtin_amdgcn_mfma_f32_16x16x32_bf16(ef[1][1].v, hb[1].v, a11, 0, 0, 0);
        a12 = __builtin_amdgcn_mfma_f32_16x16x32_bf16(ef[1][2].v, hb[2].v, a12, 0, 0, 0);
        a13 = __builtin_amdgcn_mfma_f32_16x16x32_bf16(ef[1][3].v, hb[3].v, a13, 0, 0, 0);
        a00 = __builtin_amdgcn_mfma_f32_16x16x32_bf16(ef[0][4].v, hb[4].v, a00, 0, 0, 0);
        a01 = __builtin_amdgcn_mfma_f32_16x16x32_bf16(ef[0][5].v, hb[5].v, a01, 0, 0, 0);
        a02 = __builtin_amdgcn_mfma_f32_16x16x32_bf16(ef[0][6].v, hb[6].v, a02, 0, 0, 0);
        a03 = __builtin_amdgcn_mfma_f32_16x16x32_bf16(ef[0][7].v, hb[7].v, a03, 0, 0, 0);
        a10 = __builtin_amdgcn_mfma_f32_16x16x32_bf16(ef[1][4].v, hb[4].v, a10, 0, 0, 0);
        a11 = __builtin_amdgcn_mfma_f32_16x16x32_bf16(ef[1][5].v, hb[5].v, a11, 0, 0, 0);
        a12 = __builtin_amdgcn_mfma_f32_16x16x32_bf16(ef[1][6].v, hb[6].v, a12, 0, 0, 0);
        a13 = __builtin_amdgcn_mfma_f32_16x16x32_bf16(ef[1][7].v, hb[7].v, a13, 0, 0, 0);

        // select j_own per accumulator group, tree-add, component select
        f32x4 c0 = j_own ? a10 : a00;
        f32x4 c1 = j_own ? a11 : a01;
        f32x4 c2 = j_own ? a12 : a02;
        f32x4 c3 = j_own ? a13 : a03;
        f32x4 s = (c0 + c1) + (c2 + c3);
        float y01 = (l & 1) ? s[1] : s[0];
        float y23 = (l & 1) ? s[3] : s[2];
        float y   = (l & 2) ? y23 : y01;

        // h += dt * tanh(u - (h + E h));  tanh(x) = 1 - 2/(e^{2x}+1)
        float xa = (u_cur - hval) - y;
        float E2 = __expf(2.0f * xa);
        float th = fmaf(-2.0f, __builtin_amdgcn_rcpf(E2 + 1.0f), 1.0f);
        hval = fmaf(DT_STEP, th, hval);
        if (st) hp[0] = hval;
        hp += BH;

        // pack (n_own even, n_own+1) -> dword into next buffer
        int nb = __builtin_amdgcn_mov_dpp(__float_as_int(hval), 0xB1, 0xF, 0xF, true);
        if (wrt) {
            unsigned int pk;
            asm volatile("v_cvt_pk_bf16_f32 %0, %1, %2"
                         : "=v"(pk) : "v"(hval), "v"(__int_as_float(nb)));
            *(unsigned int*)(lds + (roff ^ 512) + ((n_own >> 1) << 2)) = pk;
        }
        u_cur = u_nxt;
        u_nxt = u_n2;
        roff ^= 512;
        LBAR();
    }
    if (st) hfin[(size_t)b * NH + n_own] = hval;
}

extern "C" void kernel_launch(void* const* d_in, const int* in_sizes, int n_in,
                              void* d_out, int out_size, void* d_ws, size_t ws_size,
                              hipStream_t stream) {
    const float* x     = (const float*)d_in[0];  // [T,B,D]
    const float* U_w   = (const float*)d_in[1];  // [H,D]
    const float* U_b   = (const float*)d_in[2];  // [H]
    const float* W_log = (const float*)d_in[3];  // [H,H]
    const float* c_w   = (const float*)d_in[4];  // [O,H]
    const float* c_b   = (const float*)d_in[5];  // [O]

    float* out    = (float*)d_out;
    float* hidden = out;                          // stage hidden in d_out, then in-place GEMM
    float* hfin   = out + (long)T_STEPS * BH;     // second output chunk

    float* ws = (float*)d_ws;
    float* S  = ws;                // 65536 floats: Wexp accumulator
    float* Pa = ws + 65536;
    float* Pb = ws + 2 * 65536;
    float* u  = ws + 3 * 65536;    // 16,777,216 floats

    // Wexp = expm(W_log), Taylor K=9 (||W_log||_2 ~ 0.32 -> remainder ~1e-9)
    k_init_S<<<64, 1024, 0, stream>>>(W_log, S);
    const float* prev = W_log;
    float* cur = Pa;
    for (int k = 2; k <= 9; ++k) {
        k_expm_term<<<256, 256, 0, stream>>>(prev, W_log, cur, S, 1.0f / (float)k);
        prev = cur;
        cur = (cur == Pa) ? Pb : Pa;
    }

    // u = x @ U_w^T + U_b
    k_gemm_rows<<<4096, 256, 0, stream>>>(x, U_w, U_b, u);

    // sequential recurrence (8-wave MFMA + lgkm-only barrier), hidden -> d_out
    k_scan_bc4<<<NB, 512, 0, stream>>>(u, S, hidden, hfin);

    // out = hidden @ c_w^T + c_b, in place
    k_gemm_rows<<<4096, 256, 0, stream>>>(hidden, c_w, c_b, hidden);
}

// Round 13
// 2346.274 us; speedup vs baseline: 1.0939x; 1.0275x over previous
//
#include <hip/hip_runtime.h>
#include <math.h>

#define T_STEPS 4096
#define NB 16          // batch
#define NH 256         // hidden
#define BH (NB * NH)   // 4096 floats per time step
#define DT_STEP 0.1f

typedef __attribute__((ext_vector_type(8))) short short8;
typedef __attribute__((ext_vector_type(4))) float f32x4;

// ---------------- expm via Taylor series ----------------
__global__ __launch_bounds__(1024) void k_init_S(const float* __restrict__ A,
                                                 float* __restrict__ S) {
    int idx = blockIdx.x * 1024 + threadIdx.x;
    int i = idx >> 8, j = idx & 255;
    S[idx] = A[idx] + (i == j ? 1.0f : 0.0f);
}

__global__ __launch_bounds__(256) void k_expm_term(const float* __restrict__ Pprev,
                                                   const float* __restrict__ A,
                                                   float* __restrict__ Pnew,
                                                   float* __restrict__ S,
                                                   float invk) {
    __shared__ float prow[256];
    int i = blockIdx.x, j = threadIdx.x;
    prow[j] = Pprev[i * 256 + j];
    __syncthreads();
    float acc = 0.f;
#pragma unroll 8
    for (int m = 0; m < 256; ++m) acc = fmaf(prow[m], A[m * 256 + j], acc);
    float v = acc * invk;
    Pnew[i * 256 + j] = v;
    S[i * 256 + j] += v;
}

// ---------------- row-blocked GEMM (unchanged, works) ----------------
__global__ __launch_bounds__(256) void k_gemm_rows(const float* __restrict__ X,
                                                   const float* __restrict__ Wm,
                                                   const float* __restrict__ bias,
                                                   float* __restrict__ Out) {
    __shared__ float4 xs4[16][64];
    const int tid = threadIdx.x;
    const long r0 = (long)blockIdx.x * 16;
    float* xs = (float*)xs4;
#pragma unroll
    for (int rr = 0; rr < 16; ++rr) xs[rr * 256 + tid] = X[(r0 + rr) * 256 + tid];
    __syncthreads();

    float acc[16];
#pragma unroll
    for (int rr = 0; rr < 16; ++rr) acc[rr] = 0.f;

    const float4* wrow = (const float4*)(Wm + tid * 256);
    for (int d4 = 0; d4 < 64; ++d4) {
        float4 w = wrow[d4];
#pragma unroll
        for (int rr = 0; rr < 16; ++rr) {
            float4 xv = xs4[rr][d4];
            acc[rr] = fmaf(w.x, xv.x, acc[rr]);
            acc[rr] = fmaf(w.y, xv.y, acc[rr]);
            acc[rr] = fmaf(w.z, xv.z, acc[rr]);
            acc[rr] = fmaf(w.w, xv.w, acc[rr]);
        }
    }
    float b = bias[tid];
#pragma unroll
    for (int rr = 0; rr < 16; ++rr) Out[(r0 + rr) * 256 + tid] = acc[rr] + b;
}

// ---------------- MFMA scan v6 = round-10 + SrcC depth-8 chains ----------------
// y = E@h (E = Wexp - I bf16 A-operand; h broadcast as B across 16 cols).
// 8 waves (2/SIMD): wave w owns n-tiles 2w, 2w+1. ONE accumulator per n-tile,
// chained through all 8 kt via SrcC forwarding (m119: depth-8 chains run at
// ~peak) -> the 12 v_add combine and most of the select move into the MFMA
// pipe. VALU tail/wave drops ~85 -> ~30 instrs. Everything else = round 10.
__global__ __launch_bounds__(512)
__attribute__((amdgpu_waves_per_eu(2, 2)))
void k_scan_bc5(const float* __restrict__ u,
                const float* S,        // Wexp (f32); no restrict
                float* hidden,
                float* __restrict__ hfin) {
    const int b   = blockIdx.x;
    const int tid = threadIdx.x;
    const int w   = tid >> 6;           // wave 0..7: n-tiles 2w, 2w+1
    const int l   = tid & 63;
    const int lg  = l >> 4;             // k-group 0..3
    const int lr  = l & 15;             // row within n-tile

    __shared__ unsigned int hlds[256];  // 2 x 512B: h as bf16, linear, dbuf
    char* lds = (char*)hlds;

    union Frag { unsigned int u[4]; short8 v; };

    // ---- A-fragments: E rows for 2 n-tiles x 8 kt = 64 VGPRs ----
    Frag ef[2][8];
#pragma unroll
    for (int j = 0; j < 2; ++j) {
        const int n = ((2 * w + j) << 4) | lr;
#pragma unroll
        for (int kt = 0; kt < 8; ++kt) {
            const int k0 = kt * 32 + lg * 8;
            const float* sp = S + (size_t)n * 256 + k0;
            float e[8];
#pragma unroll
            for (int q = 0; q < 8; ++q)
                e[q] = sp[q] - ((n == k0 + q) ? 1.0f : 0.0f);
#pragma unroll
            for (int r2 = 0; r2 < 4; ++r2) {
                unsigned int pk;
                asm volatile("v_cvt_pk_bf16_f32 %0, %1, %2"
                             : "=v"(pk) : "v"(e[2 * r2]), "v"(e[2 * r2 + 1]));
                ef[j][kt].u[r2] = pk;
            }
        }
    }

    // ---- per-lane owned h element (lanes l and l|8 duplicate) ----
    const int j_own = (l >> 2) & 1;
    const int n_own = ((2 * w + j_own) << 4) | ((l >> 4) << 2) | (l & 3);
    const bool st = ((l & 8) == 0);       // storer lanes
    const bool wrt = ((l & 9) == 0);      // LDS writer lanes (even pair leader)

    if (tid < 256) hlds[tid] = 0u;        // zero both h buffers

    const float* up = u + (size_t)b * NH + n_own;
    float* hp = hidden + (size_t)b * NH + n_own;
    const float* upn = up + 2 * (size_t)BH;   // walking prefetch pointer

    float hval = 0.f;
    float u_cur = up[0];
    float u_nxt = up[BH];
    __syncthreads();

    int roff = 0;                         // byte offset of read buffer (0/512)
    for (int t = 0; t < T_STEPS; ++t) {
        float u_n2 = *upn;
        upn += (t + 3 < T_STEPS) ? BH : 0;

        // B-fragments: h broadcast (same 16B per 16-lane group)
        Frag hb[8];
#pragma unroll
        for (int kt = 0; kt < 8; ++kt)
            hb[kt].v = *(const short8*)(lds + roff + kt * 64 + lg * 16);

        // 2 accumulators, depth-8 SrcC chains (interleaved) -> combine adds
        // happen inside the MFMA pipe via C-operand accumulation.
        f32x4 a0 = {0,0,0,0}, a1 = {0,0,0,0};
#pragma unroll
        for (int kt = 0; kt < 8; ++kt) {
            a0 = __builtin_amdgcn_mfma_f32_16x16x32_bf16(ef[0][kt].v, hb[kt].v, a0, 0, 0, 0);
            a1 = __builtin_amdgcn_mfma_f32_16x16x32_bf16(ef[1][kt].v, hb[kt].v, a1, 0, 0, 0);
        }

        // slim select: tile (4 cndmask) then component (3 cndmask)
        f32x4 c = j_own ? a1 : a0;
        float y01 = (l & 1) ? c[1] : c[0];
        float y23 = (l & 1) ? c[3] : c[2];
        float y   = (l & 2) ? y23 : y01;

        // h += dt * tanh(u - (h + E h));  tanh(x) = 1 - 2/(e^{2x}+1)
        float xa = (u_cur - hval) - y;
        float E2 = __expf(2.0f * xa);
        float th = fmaf(-2.0f, __builtin_amdgcn_rcpf(E2 + 1.0f), 1.0f);
        hval = fmaf(DT_STEP, th, hval);
        if (st) hp[0] = hval;
        hp += BH;

        // pack (n_own even, n_own+1) -> dword into next buffer
        int nb = __builtin_amdgcn_mov_dpp(__float_as_int(hval), 0xB1, 0xF, 0xF, true);
        if (wrt) {
            unsigned int pk;
            asm volatile("v_cvt_pk_bf16_f32 %0, %1, %2"
                         : "=v"(pk) : "v"(hval), "v"(__int_as_float(nb)));
            *(unsigned int*)(lds + (roff ^ 512) + ((n_own >> 1) << 2)) = pk;
        }
        u_cur = u_nxt;
        u_nxt = u_n2;
        roff ^= 512;
        __syncthreads();
    }
    if (st) hfin[(size_t)b * NH + n_own] = hval;
}

extern "C" void kernel_launch(void* const* d_in, const int* in_sizes, int n_in,
                              void* d_out, int out_size, void* d_ws, size_t ws_size,
                              hipStream_t stream) {
    const float* x     = (const float*)d_in[0];  // [T,B,D]
    const float* U_w   = (const float*)d_in[1];  // [H,D]
    const float* U_b   = (const float*)d_in[2];  // [H]
    const float* W_log = (const float*)d_in[3];  // [H,H]
    const float* c_w   = (const float*)d_in[4];  // [O,H]
    const float* c_b   = (const float*)d_in[5];  // [O]

    float* out    = (float*)d_out;
    float* hidden = out;                          // stage hidden in d_out, then in-place GEMM
    float* hfin   = out + (long)T_STEPS * BH;     // second output chunk

    float* ws = (float*)d_ws;
    float* S  = ws;                // 65536 floats: Wexp accumulator
    float* Pa = ws + 65536;
    float* Pb = ws + 2 * 65536;
    float* u  = ws + 3 * 65536;    // 16,777,216 floats

    // Wexp = expm(W_log), Taylor K=9 (||W_log||_2 ~ 0.32 -> remainder ~1e-9)
    k_init_S<<<64, 1024, 0, stream>>>(W_log, S);
    const float* prev = W_log;
    float* cur = Pa;
    for (int k = 2; k <= 9; ++k) {
        k_expm_term<<<256, 256, 0, stream>>>(prev, W_log, cur, S, 1.0f / (float)k);
        prev = cur;
        cur = (cur == Pa) ? Pb : Pa;
    }

    // u = x @ U_w^T + U_b
    k_gemm_rows<<<4096, 256, 0, stream>>>(x, U_w, U_b, u);

    // sequential recurrence (depth-8 SrcC chains), hidden -> d_out
    k_scan_bc5<<<NB, 512, 0, stream>>>(u, S, hidden, hfin);

    // out = hidden @ c_w^T + c_b, in place
    k_gemm_rows<<<4096, 256, 0, stream>>>(hidden, c_w, c_b, hidden);
}

// Round 14
// 2210.980 us; speedup vs baseline: 1.1609x; 1.0612x over previous
//
#include <hip/hip_runtime.h>
#include <math.h>

#define T_STEPS 4096
#define NB 16          // batch
#define NH 256         // hidden
#define BH (NB * NH)   // 4096 floats per time step
#define DT_STEP 0.1f

typedef __attribute__((ext_vector_type(8))) short short8;
typedef __attribute__((ext_vector_type(4))) float f32x4;

// ---------------- expm via Taylor series ----------------
__global__ __launch_bounds__(1024) void k_init_S(const float* __restrict__ A,
                                                 float* __restrict__ S) {
    int idx = blockIdx.x * 1024 + threadIdx.x;
    int i = idx >> 8, j = idx & 255;
    S[idx] = A[idx] + (i == j ? 1.0f : 0.0f);
}

__global__ __launch_bounds__(256) void k_expm_term(const float* __restrict__ Pprev,
                                                   const float* __restrict__ A,
                                                   float* __restrict__ Pnew,
                                                   float* __restrict__ S,
                                                   float invk) {
    __shared__ float prow[256];
    int i = blockIdx.x, j = threadIdx.x;
    prow[j] = Pprev[i * 256 + j];
    __syncthreads();
    float acc = 0.f;
#pragma unroll 8
    for (int m = 0; m < 256; ++m) acc = fmaf(prow[m], A[m * 256 + j], acc);
    float v = acc * invk;
    Pnew[i * 256 + j] = v;
    S[i * 256 + j] += v;
}

// ---------------- row-blocked GEMM (unchanged, works) ----------------
__global__ __launch_bounds__(256) void k_gemm_rows(const float* __restrict__ X,
                                                   const float* __restrict__ Wm,
                                                   const float* __restrict__ bias,
                                                   float* __restrict__ Out) {
    __shared__ float4 xs4[16][64];
    const int tid = threadIdx.x;
    const long r0 = (long)blockIdx.x * 16;
    float* xs = (float*)xs4;
#pragma unroll
    for (int rr = 0; rr < 16; ++rr) xs[rr * 256 + tid] = X[(r0 + rr) * 256 + tid];
    __syncthreads();

    float acc[16];
#pragma unroll
    for (int rr = 0; rr < 16; ++rr) acc[rr] = 0.f;

    const float4* wrow = (const float4*)(Wm + tid * 256);
    for (int d4 = 0; d4 < 64; ++d4) {
        float4 w = wrow[d4];
#pragma unroll
        for (int rr = 0; rr < 16; ++rr) {
            float4 xv = xs4[rr][d4];
            acc[rr] = fmaf(w.x, xv.x, acc[rr]);
            acc[rr] = fmaf(w.y, xv.y, acc[rr]);
            acc[rr] = fmaf(w.z, xv.z, acc[rr]);
            acc[rr] = fmaf(w.w, xv.w, acc[rr]);
        }
    }
    float b = bias[tid];
#pragma unroll
    for (int rr = 0; rr < 16; ++rr) Out[(r0 + rr) * 256 + tid] = acc[rr] + b;
}

// ---------------- MFMA scan v7 = v6 + 8-step VMEM batching ----------------
// y = E@h (E = Wexp - I bf16 A-operand; h broadcast as B across 16 cols).
// 8 waves (2/SIMD): wave w owns n-tiles 2w, 2w+1; depth-8 SrcC chains.
// KEY CHANGE: __syncthreads drains vmcnt(0) EVERY step (m97: compiler emits
// "s_waitcnt vmcnt(0) lgkmcnt(0); s_barrier"), so any VMEM issued in a step
// puts HBM latency in that step's critical path. Batch VMEM per 8 steps:
// 8 h-values held in regs, stored once/block; next block's 8 u-values loaded
// once/block. 7 of 8 barriers then drain an empty VMEM queue (free); the one
// VMEM step pays load-latency || store-ack once.
__global__ __launch_bounds__(512)
__attribute__((amdgpu_waves_per_eu(2, 2)))
void k_scan_bc6(const float* __restrict__ u,
                const float* S,        // Wexp (f32); no restrict
                float* hidden,
                float* __restrict__ hfin) {
    const int b   = blockIdx.x;
    const int tid = threadIdx.x;
    const int w   = tid >> 6;           // wave 0..7: n-tiles 2w, 2w+1
    const int l   = tid & 63;
    const int lg  = l >> 4;             // k-group 0..3
    const int lr  = l & 15;             // row within n-tile

    __shared__ unsigned int hlds[256];  // 2 x 512B: h as bf16, linear, dbuf
    char* lds = (char*)hlds;

    union Frag { unsigned int u[4]; short8 v; };

    // ---- A-fragments: E rows for 2 n-tiles x 8 kt = 64 VGPRs ----
    Frag ef[2][8];
#pragma unroll
    for (int j = 0; j < 2; ++j) {
        const int n = ((2 * w + j) << 4) | lr;
#pragma unroll
        for (int kt = 0; kt < 8; ++kt) {
            const int k0 = kt * 32 + lg * 8;
            const float* sp = S + (size_t)n * 256 + k0;
            float e[8];
#pragma unroll
            for (int q = 0; q < 8; ++q)
                e[q] = sp[q] - ((n == k0 + q) ? 1.0f : 0.0f);
#pragma unroll
            for (int r2 = 0; r2 < 4; ++r2) {
                unsigned int pk;
                asm volatile("v_cvt_pk_bf16_f32 %0, %1, %2"
                             : "=v"(pk) : "v"(e[2 * r2]), "v"(e[2 * r2 + 1]));
                ef[j][kt].u[r2] = pk;
            }
        }
    }

    // ---- per-lane owned h element (lanes l and l|8 duplicate) ----
    const int j_own = (l >> 2) & 1;
    const int n_own = ((2 * w + j_own) << 4) | ((l >> 4) << 2) | (l & 3);
    const bool st = ((l & 8) == 0);       // storer lanes
    const bool wrt = ((l & 9) == 0);      // LDS writer lanes (even pair leader)

    if (tid < 256) hlds[tid] = 0u;        // zero both h buffers

    const int NBLK = T_STEPS / 8;         // 512 blocks of 8 steps
    const size_t blkstride = 8 * (size_t)BH;

    float* hst = hidden + (size_t)b * NH + n_own;      // store base (block k-1)
    const float* uld = u + (size_t)b * NH + n_own + blkstride;  // load base (block k+1)

    // prologue: block 0's u values
    float ucur[8], unxt[8], hsav[8];
    {
        const float* up0 = u + (size_t)b * NH + n_own;
#pragma unroll
        for (int q = 0; q < 8; ++q) ucur[q] = up0[q * (size_t)BH];
    }
    float hval = 0.f;
    __syncthreads();

    int roff = 0;                         // byte offset of read buffer (0/512)
    for (int blk = 0; blk < NBLK; ++blk) {
#pragma unroll
        for (int s = 0; s < 8; ++s) {
            if (s == 0) {
                // the ONE VMEM step of this block: deferred stores + next loads
                if (blk) {
#pragma unroll
                    for (int q = 0; q < 8; ++q)
                        if (st) hst[q * (size_t)BH] = hsav[q];
                }
#pragma unroll
                for (int q = 0; q < 8; ++q) unxt[q] = uld[q * (size_t)BH];
            }

            // B-fragments: h broadcast (same 16B per 16-lane group)
            Frag hb[8];
#pragma unroll
            for (int kt = 0; kt < 8; ++kt)
                hb[kt].v = *(const short8*)(lds + roff + kt * 64 + lg * 16);

            // 2 accumulators, depth-8 SrcC chains
            f32x4 a0 = {0,0,0,0}, a1 = {0,0,0,0};
#pragma unroll
            for (int kt = 0; kt < 8; ++kt) {
                a0 = __builtin_amdgcn_mfma_f32_16x16x32_bf16(ef[0][kt].v, hb[kt].v, a0, 0, 0, 0);
                a1 = __builtin_amdgcn_mfma_f32_16x16x32_bf16(ef[1][kt].v, hb[kt].v, a1, 0, 0, 0);
            }

            // slim select: tile then component
            f32x4 c = j_own ? a1 : a0;
            float y01 = (l & 1) ? c[1] : c[0];
            float y23 = (l & 1) ? c[3] : c[2];
            float y   = (l & 2) ? y23 : y01;

            // h += dt * tanh(u - (h + E h));  tanh(x) = 1 - 2/(e^{2x}+1)
            float xa = (ucur[s] - hval) - y;
            float E2 = __expf(2.0f * xa);
            float th = fmaf(-2.0f, __builtin_amdgcn_rcpf(E2 + 1.0f), 1.0f);
            hval = fmaf(DT_STEP, th, hval);
            hsav[s] = hval;               // deferred store (reg-held)

            // pack (n_own even, n_own+1) -> dword into next LDS buffer
            int nb = __builtin_amdgcn_mov_dpp(__float_as_int(hval), 0xB1, 0xF, 0xF, true);
            if (wrt) {
                unsigned int pk;
                asm volatile("v_cvt_pk_bf16_f32 %0, %1, %2"
                             : "=v"(pk) : "v"(hval), "v"(__int_as_float(nb)));
                *(unsigned int*)(lds + (roff ^ 512) + ((n_own >> 1) << 2)) = pk;
            }
            roff ^= 512;
            __syncthreads();
        }
        // roll register pipeline; advance pointers (clamped load ptr)
#pragma unroll
        for (int q = 0; q < 8; ++q) ucur[q] = unxt[q];
        if (blk) hst += blkstride;
        if (blk <= NBLK - 3) uld += blkstride;
    }

    // epilogue: last block's h values
#pragma unroll
    for (int q = 0; q < 8; ++q)
        if (st) hst[q * (size_t)BH] = hsav[q];
    if (st) hfin[(size_t)b * NH + n_own] = hval;
}

extern "C" void kernel_launch(void* const* d_in, const int* in_sizes, int n_in,
                              void* d_out, int out_size, void* d_ws, size_t ws_size,
                              hipStream_t stream) {
    const float* x     = (const float*)d_in[0];  // [T,B,D]
    const float* U_w   = (const float*)d_in[1];  // [H,D]
    const float* U_b   = (const float*)d_in[2];  // [H]
    const float* W_log = (const float*)d_in[3];  // [H,H]
    const float* c_w   = (const float*)d_in[4];  // [O,H]
    const float* c_b   = (const float*)d_in[5];  // [O]

    float* out    = (float*)d_out;
    float* hidden = out;                          // stage hidden in d_out, then in-place GEMM
    float* hfin   = out + (long)T_STEPS * BH;     // second output chunk

    float* ws = (float*)d_ws;
    float* S  = ws;                // 65536 floats: Wexp accumulator
    float* Pa = ws + 65536;
    float* Pb = ws + 2 * 65536;
    float* u  = ws + 3 * 65536;    // 16,777,216 floats

    // Wexp = expm(W_log), Taylor K=9 (||W_log||_2 ~ 0.32 -> remainder ~1e-9)
    k_init_S<<<64, 1024, 0, stream>>>(W_log, S);
    const float* prev = W_log;
    float* cur = Pa;
    for (int k = 2; k <= 9; ++k) {
        k_expm_term<<<256, 256, 0, stream>>>(prev, W_log, cur, S, 1.0f / (float)k);
        prev = cur;
        cur = (cur == Pa) ? Pb : Pa;
    }

    // u = x @ U_w^T + U_b
    k_gemm_rows<<<4096, 256, 0, stream>>>(x, U_w, U_b, u);

    // sequential recurrence (8-step VMEM batching), hidden -> d_out
    k_scan_bc6<<<NB, 512, 0, stream>>>(u, S, hidden, hfin);

    // out = hidden @ c_w^T + c_b, in place
    k_gemm_rows<<<4096, 256, 0, stream>>>(hidden, c_w, c_b, hidden);
}

// Round 15
// 1942.495 us; speedup vs baseline: 1.3213x; 1.1382x over previous
//
#include <hip/hip_runtime.h>
#include <math.h>

#define T_STEPS 4096
#define NB 16          // batch
#define NH 256         // hidden
#define BH (NB * NH)   // 4096 floats per time step
#define DT_STEP 0.1f

typedef __attribute__((ext_vector_type(8))) short short8;
typedef __attribute__((ext_vector_type(4))) float f32x4;

// ---------------- expm via Taylor series ----------------
__global__ __launch_bounds__(1024) void k_init_S(const float* __restrict__ A,
                                                 float* __restrict__ S) {
    int idx = blockIdx.x * 1024 + threadIdx.x;
    int i = idx >> 8, j = idx & 255;
    S[idx] = A[idx] + (i == j ? 1.0f : 0.0f);
}

__global__ __launch_bounds__(256) void k_expm_term(const float* __restrict__ Pprev,
                                                   const float* __restrict__ A,
                                                   float* __restrict__ Pnew,
                                                   float* __restrict__ S,
                                                   float invk) {
    __shared__ float prow[256];
    int i = blockIdx.x, j = threadIdx.x;
    prow[j] = Pprev[i * 256 + j];
    __syncthreads();
    float acc = 0.f;
#pragma unroll 8
    for (int m = 0; m < 256; ++m) acc = fmaf(prow[m], A[m * 256 + j], acc);
    float v = acc * invk;
    Pnew[i * 256 + j] = v;
    S[i * 256 + j] += v;
}

// ---------------- pack 256x256 f32 W (row-major, n-major) into bf16 B-frag-linear ----
// 16x16x32 MFMA B-frag: frag f = nt*8+kt; lane l holds
// B[k = kt*32 + (l>>4)*8 + j][n = nt*16 + (l&15)], j=0..7 (layout verified in scan).
__global__ __launch_bounds__(64) void k_pack_b(const float* __restrict__ W,
                                               unsigned int* __restrict__ P) {
    const int f = blockIdx.x;      // 0..127
    const int l = threadIdx.x;     // 0..63
    const int n  = ((f >> 3) << 4) | (l & 15);
    const int k0 = ((f & 7) << 5) | ((l >> 4) << 3);
    const float* sp = W + n * 256 + k0;
    unsigned int o0, o1, o2, o3;
    asm volatile("v_cvt_pk_bf16_f32 %0, %1, %2" : "=v"(o0) : "v"(sp[0]), "v"(sp[1]));
    asm volatile("v_cvt_pk_bf16_f32 %0, %1, %2" : "=v"(o1) : "v"(sp[2]), "v"(sp[3]));
    asm volatile("v_cvt_pk_bf16_f32 %0, %1, %2" : "=v"(o2) : "v"(sp[4]), "v"(sp[5]));
    asm volatile("v_cvt_pk_bf16_f32 %0, %1, %2" : "=v"(o3) : "v"(sp[6]), "v"(sp[7]));
    uint4* dst = (uint4*)(P + ((size_t)f * 64 + l) * 4);
    *dst = make_uint4(o0, o1, o2, o3);
}

// ---------------- MFMA GEMM: C[M x 256] = A[M x 256] @ W^T + bias ----------------
// W pre-packed B-frag-linear (k_pack_b). 256 threads = 4 waves; wave w owns
// rows r0 = blk*64 + w*16. LDS-free: lane l loads A row r0+(l&15), k-chunk
// (l>>4)*8 (+kt*32) f32 direct -> cvt_pk -> A-frags in regs. B-frags stream as
// coalesced 1KB uint4 loads (L2-resident). 16 indep depth-8 SrcC chains.
// In-place safe (C==A): each wave reads/writes only its own 16-row window;
// the MFMA data dependency orders all A-loads before any C-store.
__global__ __launch_bounds__(256) void k_gemm_mfma(const float* A,   // no restrict: may alias C
                                                   const unsigned int* __restrict__ P,
                                                   const float* __restrict__ bias,
                                                   float* C) {
    const int tid = threadIdx.x;
    const int w = tid >> 6, l = tid & 63;
    const size_t r0 = (size_t)blockIdx.x * 64 + w * 16;
    const int arow = l & 15;           // A row within the wave's 16-row window
    const int kg   = l >> 4;           // k-group 0..3

    union Frag { unsigned int u[4]; uint4 q; short8 v; };

    // ---- A-fragments: lane's own row, 8 k-chunks, f32 -> bf16 ----
    Frag af[8];
    const float* ap = A + (r0 + arow) * 256 + kg * 8;
#pragma unroll
    for (int kt = 0; kt < 8; ++kt) {
        float4 x0 = *(const float4*)(ap + kt * 32);
        float4 x1 = *(const float4*)(ap + kt * 32 + 4);
        asm volatile("v_cvt_pk_bf16_f32 %0, %1, %2" : "=v"(af[kt].u[0]) : "v"(x0.x), "v"(x0.y));
        asm volatile("v_cvt_pk_bf16_f32 %0, %1, %2" : "=v"(af[kt].u[1]) : "v"(x0.z), "v"(x0.w));
        asm volatile("v_cvt_pk_bf16_f32 %0, %1, %2" : "=v"(af[kt].u[2]) : "v"(x1.x), "v"(x1.y));
        asm volatile("v_cvt_pk_bf16_f32 %0, %1, %2" : "=v"(af[kt].u[3]) : "v"(x1.z), "v"(x1.w));
    }

    // ---- main: 16 n-tiles x 8 kt, acc per n-tile (depth-8 SrcC chains) ----
    f32x4 acc[16];
#pragma unroll
    for (int nt = 0; nt < 16; ++nt) acc[nt] = f32x4{0.f, 0.f, 0.f, 0.f};

#pragma unroll
    for (int nt = 0; nt < 16; ++nt) {
#pragma unroll
        for (int kt = 0; kt < 8; ++kt) {
            Frag bf_;
            bf_.q = *(const uint4*)(P + (size_t)(((nt << 3) | kt) * 64 + l) * 4);
            acc[nt] = __builtin_amdgcn_mfma_f32_16x16x32_bf16(af[kt].v, bf_.v, acc[nt], 0, 0, 0);
        }
    }

    // ---- epilogue: bias + store. C/D layout: col=l&15, row=(l>>4)*4+reg ----
#pragma unroll
    for (int nt = 0; nt < 16; ++nt) {
        float b = bias[(nt << 4) | arow];
        float* cp = C + (r0 + kg * 4) * 256 + (nt << 4) + arow;
#pragma unroll
        for (int r = 0; r < 4; ++r)
            cp[(size_t)r * 256] = acc[nt][r] + b;
    }
}

// ---------------- MFMA scan v7 (unchanged from round 14, 1781 us) ----------------
__global__ __launch_bounds__(512)
__attribute__((amdgpu_waves_per_eu(2, 2)))
void k_scan_bc6(const float* __restrict__ u,
                const float* S,        // Wexp (f32); no restrict
                float* hidden,
                float* __restrict__ hfin) {
    const int b   = blockIdx.x;
    const int tid = threadIdx.x;
    const int w   = tid >> 6;           // wave 0..7: n-tiles 2w, 2w+1
    const int l   = tid & 63;
    const int lg  = l >> 4;             // k-group 0..3
    const int lr  = l & 15;             // row within n-tile

    __shared__ unsigned int hlds[256];  // 2 x 512B: h as bf16, linear, dbuf
    char* lds = (char*)hlds;

    union Frag { unsigned int u[4]; short8 v; };

    // ---- A-fragments: E rows for 2 n-tiles x 8 kt = 64 VGPRs ----
    Frag ef[2][8];
#pragma unroll
    for (int j = 0; j < 2; ++j) {
        const int n = ((2 * w + j) << 4) | lr;
#pragma unroll
        for (int kt = 0; kt < 8; ++kt) {
            const int k0 = kt * 32 + lg * 8;
            const float* sp = S + (size_t)n * 256 + k0;
            float e[8];
#pragma unroll
            for (int q = 0; q < 8; ++q)
                e[q] = sp[q] - ((n == k0 + q) ? 1.0f : 0.0f);
#pragma unroll
            for (int r2 = 0; r2 < 4; ++r2) {
                unsigned int pk;
                asm volatile("v_cvt_pk_bf16_f32 %0, %1, %2"
                             : "=v"(pk) : "v"(e[2 * r2]), "v"(e[2 * r2 + 1]));
                ef[j][kt].u[r2] = pk;
            }
        }
    }

    // ---- per-lane owned h element (lanes l and l|8 duplicate) ----
    const int j_own = (l >> 2) & 1;
    const int n_own = ((2 * w + j_own) << 4) | ((l >> 4) << 2) | (l & 3);
    const bool st = ((l & 8) == 0);       // storer lanes
    const bool wrt = ((l & 9) == 0);      // LDS writer lanes (even pair leader)

    if (tid < 256) hlds[tid] = 0u;        // zero both h buffers

    const int NBLK = T_STEPS / 8;         // 512 blocks of 8 steps
    const size_t blkstride = 8 * (size_t)BH;

    float* hst = hidden + (size_t)b * NH + n_own;      // store base (block k-1)
    const float* uld = u + (size_t)b * NH + n_own + blkstride;  // load base (block k+1)

    // prologue: block 0's u values
    float ucur[8], unxt[8], hsav[8];
    {
        const float* up0 = u + (size_t)b * NH + n_own;
#pragma unroll
        for (int q = 0; q < 8; ++q) ucur[q] = up0[q * (size_t)BH];
    }
    float hval = 0.f;
    __syncthreads();

    int roff = 0;                         // byte offset of read buffer (0/512)
    for (int blk = 0; blk < NBLK; ++blk) {
#pragma unroll
        for (int s = 0; s < 8; ++s) {
            if (s == 0) {
                // the ONE VMEM step of this block: deferred stores + next loads
                if (blk) {
#pragma unroll
                    for (int q = 0; q < 8; ++q)
                        if (st) hst[q * (size_t)BH] = hsav[q];
                }
#pragma unroll
                for (int q = 0; q < 8; ++q) unxt[q] = uld[q * (size_t)BH];
            }

            // B-fragments: h broadcast (same 16B per 16-lane group)
            Frag hb[8];
#pragma unroll
            for (int kt = 0; kt < 8; ++kt)
                hb[kt].v = *(const short8*)(lds + roff + kt * 64 + lg * 16);

            // 2 accumulators, depth-8 SrcC chains
            f32x4 a0 = {0,0,0,0}, a1 = {0,0,0,0};
#pragma unroll
            for (int kt = 0; kt < 8; ++kt) {
                a0 = __builtin_amdgcn_mfma_f32_16x16x32_bf16(ef[0][kt].v, hb[kt].v, a0, 0, 0, 0);
                a1 = __builtin_amdgcn_mfma_f32_16x16x32_bf16(ef[1][kt].v, hb[kt].v, a1, 0, 0, 0);
            }

            // slim select: tile then component
            f32x4 c = j_own ? a1 : a0;
            float y01 = (l & 1) ? c[1] : c[0];
            float y23 = (l & 1) ? c[3] : c[2];
            float y   = (l & 2) ? y23 : y01;

            // h += dt * tanh(u - (h + E h));  tanh(x) = 1 - 2/(e^{2x}+1)
            float xa = (ucur[s] - hval) - y;
            float E2 = __expf(2.0f * xa);
            float th = fmaf(-2.0f, __builtin_amdgcn_rcpf(E2 + 1.0f), 1.0f);
            hval = fmaf(DT_STEP, th, hval);
            hsav[s] = hval;               // deferred store (reg-held)

            // pack (n_own even, n_own+1) -> dword into next LDS buffer
            int nb = __builtin_amdgcn_mov_dpp(__float_as_int(hval), 0xB1, 0xF, 0xF, true);
            if (wrt) {
                unsigned int pk;
                asm volatile("v_cvt_pk_bf16_f32 %0, %1, %2"
                             : "=v"(pk) : "v"(hval), "v"(__int_as_float(nb)));
                *(unsigned int*)(lds + (roff ^ 512) + ((n_own >> 1) << 2)) = pk;
            }
            roff ^= 512;
            __syncthreads();
        }
        // roll register pipeline; advance pointers (clamped load ptr)
#pragma unroll
        for (int q = 0; q < 8; ++q) ucur[q] = unxt[q];
        if (blk) hst += blkstride;
        if (blk <= NBLK - 3) uld += blkstride;
    }

    // epilogue: last block's h values
#pragma unroll
    for (int q = 0; q < 8; ++q)
        if (st) hst[q * (size_t)BH] = hsav[q];
    if (st) hfin[(size_t)b * NH + n_own] = hval;
}

extern "C" void kernel_launch(void* const* d_in, const int* in_sizes, int n_in,
                              void* d_out, int out_size, void* d_ws, size_t ws_size,
                              hipStream_t stream) {
    const float* x     = (const float*)d_in[0];  // [T,B,D]
    const float* U_w   = (const float*)d_in[1];  // [H,D]
    const float* U_b   = (const float*)d_in[2];  // [H]
    const float* W_log = (const float*)d_in[3];  // [H,H]
    const float* c_w   = (const float*)d_in[4];  // [O,H]
    const float* c_b   = (const float*)d_in[5];  // [O]

    float* out    = (float*)d_out;
    float* hidden = out;                          // stage hidden in d_out, then in-place GEMM
    float* hfin   = out + (long)T_STEPS * BH;     // second output chunk

    float* ws = (float*)d_ws;
    float* S  = ws;                // 65536 floats: Wexp accumulator
    float* Pa = ws + 65536;        // expm scratch; reused as packed U_w (bf16 frags)
    float* Pb = ws + 2 * 65536;    // expm scratch; reused as packed c_w (bf16 frags)
    float* u  = ws + 3 * 65536;    // 16,777,216 floats

    // Wexp = expm(W_log), Taylor K=9 (||W_log||_2 ~ 0.32 -> remainder ~1e-9)
    k_init_S<<<64, 1024, 0, stream>>>(W_log, S);
    const float* prev = W_log;
    float* cur = Pa;
    for (int k = 2; k <= 9; ++k) {
        k_expm_term<<<256, 256, 0, stream>>>(prev, W_log, cur, S, 1.0f / (float)k);
        prev = cur;
        cur = (cur == Pa) ? Pb : Pa;
    }

    // pack weights into bf16 B-frag-linear layout (Pa/Pb are dead after expm)
    unsigned int* PUw = (unsigned int*)Pa;
    unsigned int* Pcw = (unsigned int*)Pb;
    k_pack_b<<<128, 64, 0, stream>>>(U_w, PUw);
    k_pack_b<<<128, 64, 0, stream>>>(c_w, Pcw);

    // u = x @ U_w^T + U_b   (bf16 MFMA, f32 accumulate/output)
    k_gemm_mfma<<<1024, 256, 0, stream>>>(x, PUw, U_b, u);

    // sequential recurrence (8-step VMEM batching), hidden -> d_out
    k_scan_bc6<<<NB, 512, 0, stream>>>(u, S, hidden, hfin);

    // out = hidden @ c_w^T + c_b, in place (bf16 MFMA)
    k_gemm_mfma<<<1024, 256, 0, stream>>>(hidden, Pcw, c_b, hidden);
}